// Round 1
// 1268.919 us; speedup vs baseline: 1.1126x; 1.1126x over previous
//
#include <hip/hip_runtime.h>

#define NN    50000
#define EE    800000
#define DIN   512
#define DH    128
#define NC    64
#define KITER 10
#define NSB   196          // ceil(NN/256) scan blocks

typedef __attribute__((ext_vector_type(8))) short short8;
typedef __attribute__((ext_vector_type(4))) short short4v;
typedef __attribute__((ext_vector_type(4))) float f32x4;

static __device__ __forceinline__ float bf2f(short u) {
  unsigned int x = ((unsigned int)(unsigned short)u) << 16;
  return __builtin_bit_cast(float, x);
}
static __device__ __forceinline__ short f2bf(float f) {
  unsigned int x = __builtin_bit_cast(unsigned int, f);
  unsigned int lsb = (x >> 16) & 1u;
  x += 0x7fffu + lsb;                    // round-to-nearest-even
  return (short)(x >> 16);
}

// ---- f32 16B copy: X -> out0 (byte exact) ----------------------------------
__global__ void k_copy4(const f32x4* __restrict__ src, f32x4* __restrict__ dst) {
  int i = blockIdx.x * 256 + threadIdx.x;       // 6.4M f32x4 exact
  dst[i] = src[i];
}

// ---- f32 -> bf16 pack (reads the out0 copy, writes Xb) ---------------------
__global__ void k_f2bv(const float* __restrict__ src, short* __restrict__ dst) {
  int j = (blockIdx.x * 256 + threadIdx.x) * 4;
  f32x4 s = *(const f32x4*)(src + j);
  short4v o = { f2bf(s.x), f2bf(s.y), f2bf(s.z), f2bf(s.w) };
  *(short4v*)(dst + j) = o;
}

// ---- CSR build -------------------------------------------------------------
__global__ void k_count(const int* __restrict__ ei, int* __restrict__ cnt) {
  int e = blockIdx.x * 256 + threadIdx.x;
  if (e < EE) atomicAdd(&cnt[ei[EE + e]], 1);
}

__global__ void k_dinv(const int* __restrict__ cnt, float* __restrict__ dinv) {
  int i = blockIdx.x * 256 + threadIdx.x;
  if (i < NN) dinv[i] = rsqrtf((float)(cnt[i] + 1));   // +1 self-loop
}

// ---- parallel 3-phase scan (replaces 151us single-block k_scan) ------------
// phase 1: per-block inclusive scan, local values into rp[i+1], totals to bsum
__global__ __launch_bounds__(256) void k_scan1(const int* __restrict__ cnt,
                                               int* __restrict__ rp,
                                               int* __restrict__ bsum) {
  __shared__ int wsum[4];
  int t = threadIdx.x, lane = t & 63, w = t >> 6;
  int i = blockIdx.x * 256 + t;
  int x = (i < NN) ? cnt[i] : 0;
  #pragma unroll
  for (int off = 1; off < 64; off <<= 1) {
    int y = __shfl_up(x, off);
    if (lane >= off) x += y;
  }
  if (lane == 63) wsum[w] = x;
  __syncthreads();
  int woff = 0;
  #pragma unroll
  for (int j = 0; j < 4; ++j) if (j < w) woff += wsum[j];
  x += woff;
  if (i < NN) rp[i + 1] = x;
  if (t == 255) bsum[blockIdx.x] = x;   // block inclusive total (pad is 0)
}

// phase 2: exclusive scan of the 196 block totals, in place (single block)
__global__ __launch_bounds__(256) void k_scan2(int* __restrict__ bsum) {
  __shared__ int wsum[4];
  int t = threadIdx.x, lane = t & 63, w = t >> 6;
  int orig = (t < NSB) ? bsum[t] : 0;
  int x = orig;
  #pragma unroll
  for (int off = 1; off < 64; off <<= 1) {
    int y = __shfl_up(x, off);
    if (lane >= off) x += y;
  }
  if (lane == 63) wsum[w] = x;
  __syncthreads();
  int woff = 0;
  #pragma unroll
  for (int j = 0; j < 4; ++j) if (j < w) woff += wsum[j];
  x += woff;
  if (t < NSB) bsum[t] = x - orig;      // exclusive prefix
}

// phase 3: add block offsets; rp[0] = 0
__global__ __launch_bounds__(256) void k_scan3(int* __restrict__ rp,
                                               const int* __restrict__ bsum) {
  int i = blockIdx.x * 256 + threadIdx.x;
  if (i == 0) rp[0] = 0;
  if (i < NN) rp[i + 1] += bsum[blockIdx.x];
}

__global__ void k_fill(const int* __restrict__ ei, const int* __restrict__ rp,
                       int* __restrict__ fill, const float* __restrict__ dinv,
                       int* __restrict__ col, float* __restrict__ val) {
  int e = blockIdx.x * 256 + threadIdx.x;
  if (e < EE) {
    int s = ei[e], d = ei[EE + e];
    int pos = atomicAdd(&fill[d], 1);
    int idx = rp[d] + pos;
    col[idx] = s;
    val[idx] = dinv[s] * dinv[d];
  }
}

// ---- GEMM1: h1 = relu(Xb @ W1b^T + b1); writes bf16 h1 AND f32 state init --
__global__ __launch_bounds__(256) void k_gemm1(const short* __restrict__ Xb,
                                               const short* __restrict__ W1b,
                                               const float* __restrict__ B1,
                                               short* __restrict__ h1,
                                               float* __restrict__ st0) {
  int w = threadIdx.x >> 6;
  int lane = threadIdx.x & 63;
  int q = lane >> 4, r = lane & 15;
  int m0 = blockIdx.x * 64 + w * 16;

  f32x4 acc[8];
  #pragma unroll
  for (int i = 0; i < 8; ++i) acc[i] = (f32x4){0.f, 0.f, 0.f, 0.f};

  int row_a = m0 + r;
  if (row_a >= NN) row_a = NN - 1;            // clamp loads, stores masked
  const short* xrow = Xb + (size_t)row_a * DIN + q * 8;

  for (int kc = 0; kc < DIN / 32; ++kc) {
    short8 a = *(const short8*)(xrow + kc * 32);
    #pragma unroll
    for (int nt = 0; nt < 8; ++nt) {
      const short* wrow = W1b + (size_t)(nt * 16 + r) * DIN + q * 8 + kc * 32;
      short8 b = *(const short8*)wrow;
      acc[nt] = __builtin_amdgcn_mfma_f32_16x16x32_bf16(a, b, acc[nt], 0, 0, 0);
    }
  }

  #pragma unroll
  for (int nt = 0; nt < 8; ++nt) {
    int n = nt * 16 + r;                      // C/D: col = lane&15
    float bias = B1[n];
    #pragma unroll
    for (int reg = 0; reg < 4; ++reg) {
      int row = m0 + q * 4 + reg;             // C/D: row = quad*4 + reg
      if (row < NN) {
        float v = acc[nt][reg] + bias;
        v = v > 0.f ? v : 0.f;
        h1[(size_t)row * DH + n] = f2bf(v);
        st0[(size_t)row * DH + n] = v;
      }
    }
  }
}

// ---- one APPNP step: f32 state, bf16 h0 term -------------------------------
__global__ __launch_bounds__(256) void k_step(const int* __restrict__ rp,
                                              const int* __restrict__ col,
                                              const float* __restrict__ val,
                                              const float* __restrict__ dinv,
                                              const float* __restrict__ xc,
                                              const short* __restrict__ h0,
                                              float* __restrict__ xn) {
  int g = blockIdx.x * 256 + threadIdx.x;
  int node = g >> 5, lane = g & 31;           // 32 lanes/node, f32x4 each
  int beg = rp[node], end = rp[node + 1];
  const f32x4* xcv = (const f32x4*)xc;
  f32x4 acc = (f32x4){0.f, 0.f, 0.f, 0.f};
  for (int e = beg; e < end; ++e) {
    int s = col[e];
    float wgt = val[e];
    acc += xcv[(size_t)s * 32 + lane] * wgt;
  }
  float di = dinv[node];
  acc += xcv[(size_t)node * 32 + lane] * (di * di);   // self-loop
  short4v hv = ((const short4v*)h0)[node * 32 + lane];
  f32x4 h = { bf2f(hv.x), bf2f(hv.y), bf2f(hv.z), bf2f(hv.w) };
  ((f32x4*)xn)[(size_t)node * 32 + lane] = acc * 0.9f + h * 0.1f;
}

// ---- scalar APPNP for the bias term: v = APPNP(1) --------------------------
__global__ void k_vinit(float* __restrict__ v) {
  int i = blockIdx.x * 256 + threadIdx.x;
  if (i < NN) v[i] = 1.f;
}

__global__ void k_vstep(const int* __restrict__ rp, const int* __restrict__ col,
                        const float* __restrict__ val, const float* __restrict__ dinv,
                        const float* __restrict__ vc, float* __restrict__ vn) {
  int i = blockIdx.x * 256 + threadIdx.x;
  if (i >= NN) return;
  float s = 0.f;
  int end = rp[i + 1];
  for (int e = rp[i]; e < end; ++e) s += val[e] * vc[col[e]];
  float di = dinv[i];
  s += di * di * vc[i];
  vn[i] = 0.9f * s + 0.1f;
}

// ---- GEMM2: out2 = emb1 @ W2^T + v*b2, all f32 -----------------------------
__global__ __launch_bounds__(256) void k_gemm2(const float* __restrict__ emb,
                                               const float* __restrict__ W2,
                                               const float* __restrict__ B2,
                                               const float* __restrict__ v,
                                               float* __restrict__ out2) {
  __shared__ float sW[NC][DH + 1];
  __shared__ float sb[NC];
  __shared__ float sE[32][DH + 1];
  int t = threadIdx.x;
  for (int i = t; i < NC * DH; i += 256) sW[i / DH][i % DH] = W2[i];
  if (t < NC) sb[t] = B2[t];
  int n0 = blockIdx.x * 32;
  for (int i = t; i < 32 * DH; i += 256) {
    int nl = i / DH, kk = i % DH;
    int node = n0 + nl;
    sE[nl][kk] = (node < NN) ? emb[(size_t)node * DH + kk] : 0.f;
  }
  __syncthreads();
  int nl = t >> 3, cb = t & 7;
  int node = n0 + nl;
  if (node >= NN) return;
  float vn = v[node];
  #pragma unroll
  for (int j = 0; j < 8; ++j) {
    int c = cb + 8 * j;
    float s = 0.f;
    #pragma unroll 4
    for (int k = 0; k < DH; ++k) s += sE[nl][k] * sW[c][k];
    s += vn * sb[c];
    out2[(size_t)node * NC + c] = s;
  }
}

extern "C" void kernel_launch(void* const* d_in, const int* in_sizes, int n_in,
                              void* d_out, int out_size, void* d_ws, size_t ws_size,
                              hipStream_t stream) {
  const float* X  = (const float*)d_in[0];   // [50000,512] f32 (102.4MB)
  const int*   EI = (const int*)d_in[1];     // [2,800000] int32
  const float* W1 = (const float*)d_in[2];   // [128,512] f32
  const float* B1 = (const float*)d_in[3];   // [128] f32
  const float* W2 = (const float*)d_in[4];   // [64,128] f32
  const float* B2 = (const float*)d_in[5];   // [64] f32

  // ---- d_out: 35.2M f32 = 140.8MB ----
  float* out0 = (float*)d_out;                    // [0, 102.4MB): x passthrough
  float* out1 = (float*)d_out + 25600000;         // [102.4, 128MB): emb1
  float* out2 = (float*)d_out + 32000000;         // [128, 140.8MB): out

  // ---- ALL scratch in d_in[0]'s 102.4MB region (X consumed first). d_ws unused.
  char* xr = (char*)d_in[0];
  float* bufB = (float*)(xr);                 // [0, 25.6MB) f32 (Xb dead by then)
  short* Xb   = (short*)(xr);                 // [0, 51.2MB) bf16 (gemm1 input)
  float* bufA = (float*)(xr + 51200000);      // [51.2, 76.8MB) f32
  short* h1   = (short*)(xr + 76800000);      // [76.8, 89.6MB) bf16
  int*   col  = (int*)  (xr + 89600000);      // 3.2MB
  float* val  = (float*)(xr + 92800000);      // 3.2MB
  int*   rp   = (int*)  (xr + 96000000);      // 200,004B
  int*   cnt  = (int*)  (xr + 96200192);      // 200,000B
  int*   fill = (int*)  (xr + 96400192);      // 200,000B
  float* dinv = (float*)(xr + 96600192);      // 200,000B
  float* va   = (float*)(xr + 96800192);
  float* vb   = (float*)(xr + 97000192);
  short* W1b  = (short*)(xr + 97200192);      // 128KB, ends ~97.33MB
  int*   bsum = (int*)  (xr + 97400192);      // 784B scan block sums

  // 1) out0 = x, byte-exact (must be first; then X region becomes scratch)
  k_copy4<<<dim3(25000), dim3(256), 0, stream>>>((const f32x4*)X, (f32x4*)out0);
  // 2) Xb = bf16(x), reading the copy in out0 (X region now being overwritten)
  k_f2bv <<<dim3(25000), dim3(256), 0, stream>>>(out0, Xb);
  // 3) W1 -> bf16
  k_f2bv <<<dim3(64),    dim3(256), 0, stream>>>(W1, W1b);

  hipMemsetAsync(cnt, 0, 400000, stream);     // cnt + fill (contiguous)
  k_count<<<dim3(3125), dim3(256), 0, stream>>>(EI, cnt);
  k_dinv <<<dim3(196),  dim3(256), 0, stream>>>(cnt, dinv);
  // parallel 3-phase scan (was: single-block k_scan, 151us)
  k_scan1<<<dim3(NSB), dim3(256), 0, stream>>>(cnt, rp, bsum);
  k_scan2<<<dim3(1),   dim3(256), 0, stream>>>(bsum);
  k_scan3<<<dim3(NSB), dim3(256), 0, stream>>>(rp, bsum);
  k_fill <<<dim3(3125), dim3(256), 0, stream>>>(EI, rp, fill, dinv, col, val);

  // h1 (bf16) + state init (f32, exact pre-rounding values)
  k_gemm1<<<dim3(782),  dim3(256), 0, stream>>>(Xb, W1b, B1, h1, bufA);

  // 10 steps: A->B (overwrites dead Xb region), B->A, ...; ends in bufA
  for (int it = 0; it < KITER; ++it) {
    const float* xc = (it & 1) ? bufB : bufA;
    float*       xn = (it & 1) ? bufA : bufB;
    k_step<<<dim3(6250), dim3(256), 0, stream>>>(rp, col, val, dinv, xc, h1, xn);
  }

  k_vinit<<<dim3(196), dim3(256), 0, stream>>>(va);
  for (int it = 0; it < KITER; ++it) {
    const float* vc = (it & 1) ? vb : va;
    float*       vn = (it & 1) ? va : vb;
    k_vstep<<<dim3(196), dim3(256), 0, stream>>>(rp, col, val, dinv, vc, vn);
  }

  // out2 = emb1 @ W2^T + APPNP(1)*b2   (all f32)
  k_gemm2<<<dim3(1563), dim3(256), 0, stream>>>(bufA, W2, B2, va, out2);
  // out1 = emb1 (f32 copy, 25.6MB)
  k_copy4<<<dim3(6250), dim3(256), 0, stream>>>((const f32x4*)bufA, (f32x4*)out1);
}